// Round 5
// baseline (237.837 us; speedup 1.0000x reference)
//
#include <hip/hip_runtime.h>

typedef float v2f __attribute__((ext_vector_type(2)));
typedef float v4f __attribute__((ext_vector_type(4)));

#define DD   187   // input dim
#define HH   50    // hidden
#define PH   64    // padded hidden: 8 lanes x 8 neurons
#define NPL  2     // v4f per lane (8 neurons/lane)
#define NC   5     // classes
#define RPB  32    // rows per block
#define BLK  256   // threads per block
#define DCH  64    // d-chunk
#define NCHUNK 3   // ceil(187/64)
#define BETA 0.9f
#define GRP  16    // steps staged in LDS between flushes
#define SLAB (RPB * NC)            // 160 dwords per step
#define PH1F (RPB * 65 + DCH * PH) // 2080 + 4096 = 6176 floats (phase 1)
#define SLABF (2 * GRP * SLAB)     // 5120 floats (phase 2)
#define LDSF (PH1F > SLABF ? PH1F : SLABF)

__device__ __forceinline__ float dpp_xor1(float v) {    // quad_perm [1,0,3,2]
    return __builtin_bit_cast(float,
        __builtin_amdgcn_mov_dpp(__builtin_bit_cast(int, v), 0xB1, 0xF, 0xF, true));
}
__device__ __forceinline__ float dpp_xor2(float v) {    // quad_perm [2,3,0,1]
    return __builtin_bit_cast(float,
        __builtin_amdgcn_mov_dpp(__builtin_bit_cast(int, v), 0x4E, 0xF, 0xF, true));
}
__device__ __forceinline__ float dpp_hmirror(float v) { // row_half_mirror: lane i <-> 7-i in each 8-group
    return __builtin_bit_cast(float,
        __builtin_amdgcn_mov_dpp(__builtin_bit_cast(int, v), 0x141, 0xF, 0xF, true));
}

__device__ __forceinline__ float spike1(float m) {
    // exact (m > 1) ? 1 : 0  (verified rounds 1-4)
    float t = fmaf(m, 0x1.0p60f, -0x1.0p60f);
    return fminf(fmaxf(t, 0.f), 1.f);
}
__device__ __forceinline__ v4f spike4(v4f m) {
    const v4f BIG  = { 0x1.0p60f,  0x1.0p60f,  0x1.0p60f,  0x1.0p60f};
    const v4f NBIG = {-0x1.0p60f, -0x1.0p60f, -0x1.0p60f, -0x1.0p60f};
    const v4f ONE  = {1.f, 1.f, 1.f, 1.f};
    const v4f ZERO = {0.f, 0.f, 0.f, 0.f};
    v4f t = __builtin_elementwise_fma(m, BIG, NBIG);
    return __builtin_elementwise_min(__builtin_elementwise_max(t, ZERO), ONE);
}

__global__ __launch_bounds__(BLK, 4)   // cap 128 VGPR -> 4 waves/SIMD, no spills if state fits
void snn_kernel(const float* __restrict__ x,
                const float* __restrict__ W1,
                const float* __restrict__ b1,
                const float* __restrict__ W2,
                const float* __restrict__ b2,
                const int*   __restrict__ nsp,
                float* __restrict__ out, int Brows)
{
    __shared__ alignas(16) float smem[LDSF];
    float* xs  = smem;                 // RPB*65
    float* w1t = smem + RPB * 65;      // DCH*PH
    float* spk_lds = smem;             // GRP*SLAB
    float* mem_lds = smem + GRP * SLAB;

    const int tid = threadIdx.x;
    const int p   = tid >> 3;          // row within block (0..31)
    const int o   = tid & 7;           // octet lane: owns neurons o*8..o*8+7, class o (o<5)
    const int row0 = blockIdx.x * RPB;
    const int NS  = nsp[0];

    // ---------------- Phase 1: cur1 = x @ W1^T (d-chunked) ----------------
    v4f acc[NPL];
#pragma unroll
    for (int i = 0; i < NPL; ++i) acc[i] = (v4f){0.f, 0.f, 0.f, 0.f};

    for (int ch = 0; ch < NCHUNK; ++ch) {
        const int d0 = ch * DCH;
        for (int i = tid; i < RPB * DCH; i += BLK) {
            int r = i >> 6, dd = i & 63;
            int d = d0 + dd;
            xs[r * 65 + dd] = (d < DD) ? x[(size_t)(row0 + r) * DD + d] : 0.f;
        }
        for (int i = tid; i < DCH * PH; i += BLK) {
            int h = i >> 6, dd = i & 63;     // i = h*64 + dd
            int d = d0 + dd;
            w1t[dd * PH + h] = (h < HH && d < DD) ? W1[h * DD + d] : 0.f;
        }
        __syncthreads();

        const float* xr = xs + p * 65;
#pragma unroll 4
        for (int d = 0; d < DCH; ++d) {
            float xv = xr[d];                                  // broadcast within octet
            const v4f* wr = (const v4f*)(w1t + d * PH + o * 8); // 32B-aligned -> ds_read_b128
            v4f xvv = {xv, xv, xv, xv};
#pragma unroll
            for (int i = 0; i < NPL; ++i)
                acc[i] = __builtin_elementwise_fma(xvv, wr[i], acc[i]);
        }
        __syncthreads();
    }

    // cur1 = acc + b1 (pad neurons stay 0 -> never spike)
    v4f c1[NPL];
#pragma unroll
    for (int i = 0; i < NPL; ++i) {
        v4f bb;
#pragma unroll
        for (int e = 0; e < 4; ++e) {
            int h = o * 8 + 4 * i + e;
            bb[e] = (h < HH) ? b1[h] : 0.f;
        }
        c1[i] = acc[i] + bb;
    }

    // W2 fragments: 5 classes x 2 v4f = 40 VGPR
    v4f w2r[NC][NPL];
#pragma unroll
    for (int c = 0; c < NC; ++c)
#pragma unroll
        for (int i = 0; i < NPL; ++i) {
#pragma unroll
            for (int e = 0; e < 4; ++e) {
                int h = o * 8 + 4 * i + e;
                w2r[c][i][e] = (h < HH) ? W2[c * HH + h] : 0.f;
            }
        }
    const float b2own = b2[(o < NC) ? o : (NC - 1)];

    // ---------------- Phase 2: LIF recurrence ----------------
    v4f m1[NPL], s1[NPL];
#pragma unroll
    for (int i = 0; i < NPL; ++i) { m1[i] = (v4f){0,0,0,0}; s1[i] = (v4f){0,0,0,0}; }
    float mo = 0.f, so = 0.f;          // layer-2 state for owned class

    const size_t stride = (size_t)Brows * NC;
    const int lslot = p * NC + o;      // LDS slot (o<5 only)
    const v4f BETA4 = {BETA, BETA, BETA, BETA};

    __syncthreads();                   // phase-1 LDS -> slab reuse

    int t0 = 0;
    while (t0 < NS) {
        const int steps = (NS - t0 < GRP) ? (NS - t0) : GRP;

        for (int u = 0; u < steps; ++u) {
            v4f cp[NC];
#pragma unroll
            for (int c = 0; c < NC; ++c) cp[c] = (v4f){0,0,0,0};
#pragma unroll
            for (int i = 0; i < NPL; ++i) {
                v4f m = __builtin_elementwise_fma(BETA4, m1[i], c1[i]) - s1[i];
                m1[i] = m;
                v4f s = spike4(m);
                s1[i] = s;
#pragma unroll
                for (int c = 0; c < NC; ++c)
                    cp[c] = __builtin_elementwise_fma(s, w2r[c][i], cp[c]);
            }
            // horizontal (4-wide) + 3-hop octet butterfly -> all 8 lanes have each sum
            float cur2[NC];
#pragma unroll
            for (int c = 0; c < NC; ++c) {
                v2f lo = {cp[c][0], cp[c][1]};
                v2f hi = {cp[c][2], cp[c][3]};
                v2f hs = lo + hi;
                float r = hs.x + hs.y;
                r += dpp_xor1(r);
                r += dpp_xor2(r);
                r += dpp_hmirror(r);
                cur2[c] = r;
            }
            float cown = cur2[0];
            cown = (o == 1) ? cur2[1] : cown;
            cown = (o == 2) ? cur2[2] : cown;
            cown = (o == 3) ? cur2[3] : cown;
            cown = (o == 4) ? cur2[4] : cown;

            mo = fmaf(BETA, mo, cown + b2own) - so;   // so == reset from previous step
            so = spike1(mo);

            if (o < NC) {
                spk_lds[u * SLAB + lslot] = so;
                mem_lds[u * SLAB + lslot] = mo;
            }
        }

        __syncthreads();   // slab complete

        // coalesced flush: 16B chunks; steps*40 chunks
        const int totalChunks = steps * (SLAB / 4);
        for (int c = tid; c < totalChunks; c += BLK) {
            int u   = c / (SLAB / 4);
            int pos = c - u * (SLAB / 4);
            v4f sv = *(const v4f*)(spk_lds + u * SLAB + pos * 4);
            v4f mv = *(const v4f*)(mem_lds + u * SLAB + pos * 4);
            float* sp = out + (size_t)(t0 + u) * stride + (size_t)row0 * NC + pos * 4;
            float* mp = sp + (size_t)NS * stride;
            *(v4f*)sp = sv;
            *(v4f*)mp = mv;
        }

        __syncthreads();   // slab reusable
        t0 += steps;
    }
}

extern "C" void kernel_launch(void* const* d_in, const int* in_sizes, int n_in,
                              void* d_out, int out_size, void* d_ws, size_t ws_size,
                              hipStream_t stream) {
    const float* x  = (const float*)d_in[0];
    const float* W1 = (const float*)d_in[1];
    const float* b1 = (const float*)d_in[2];
    const float* W2 = (const float*)d_in[3];
    const float* b2 = (const float*)d_in[4];
    const int*   ns = (const int*)d_in[5];
    int B = in_sizes[0] / DD;          // 32768
    int nblocks = B / RPB;             // 1024 -> 4 blocks/CU, 16 waves/CU
    snn_kernel<<<nblocks, BLK, 0, stream>>>(x, W1, b1, W2, b2, ns, (float*)d_out, B);
}